// Round 1
// baseline (696.077 us; speedup 1.0000x reference)
//
#include <hip/hip_runtime.h>
#include <math.h>

typedef _Float16 f16;
typedef _Float16 f16x8 __attribute__((ext_vector_type(8)));
typedef float f32x4 __attribute__((ext_vector_type(4)));

#define K_HID 2048
#define N_SEQ 4096
#define N_BATCH 2
#define M_ROWS 8192   // B*S

// ---------------- f32 -> f16 conversion (8 elems/thread) ----------------
__global__ __launch_bounds__(256) void cvt_f32_to_f16(const float* __restrict__ x,
                                                      f16* __restrict__ y, int n) {
  int i = (blockIdx.x * 256 + threadIdx.x) * 8;
  if (i >= n) return;
  float4 a = *(const float4*)(x + i);
  float4 b = *(const float4*)(x + i + 4);
  f16x8 o;
  o[0] = (f16)a.x; o[1] = (f16)a.y; o[2] = (f16)a.z; o[3] = (f16)a.w;
  o[4] = (f16)b.x; o[5] = (f16)b.y; o[6] = (f16)b.z; o[7] = (f16)b.w;
  *(f16x8*)(y + i) = o;
}

// -------- weight transpose+convert: W[K][N] f32 -> Wt[N][K] f16 ----------
__global__ __launch_bounds__(256) void transpose_cvt(const float* __restrict__ W0,
                                                     const float* __restrict__ W1,
                                                     const float* __restrict__ W2,
                                                     const float* __restrict__ W3,
                                                     f16* __restrict__ WT) {
  const float* W = (blockIdx.z == 0) ? W0 : (blockIdx.z == 1) ? W1
                 : (blockIdx.z == 2) ? W2 : W3;
  f16* Wt = WT + (size_t)blockIdx.z * K_HID * K_HID;
  __shared__ float tile[32][33];
  int bx = blockIdx.x * 32;   // n base
  int by = blockIdx.y * 32;   // k base
  int x = threadIdx.x & 31;
  int y = threadIdx.x >> 5;   // 0..7
  for (int i = 0; i < 32; i += 8)
    tile[y + i][x] = W[(size_t)(by + y + i) * K_HID + bx + x];
  __syncthreads();
  for (int i = 0; i < 32; i += 8)
    Wt[(size_t)(bx + y + i) * K_HID + by + x] = (f16)tile[x][y + i];
}

// ---------------- GEMM: C[M][N] = A[M][K] * Bt[N][K]^T ----------------
// 128x128 tile, BK=32, 256 threads (4 waves, each 64x64 = 4x4 mfma subtiles).
// MFMA 16x16x32 f16: A-frag A[m=lane&15][k=quad*8+j], B-frag Bt[n=lane&15][k=quad*8+j],
// C/D: row=quad*4+reg, col=lane&15  (verified layout, guide §3).
template <typename OutT>
__global__ __launch_bounds__(256) void gemm_bt(const f16* __restrict__ A,
                                               const f16* __restrict__ BtBase,
                                               OutT* __restrict__ CBase,
                                               int M, int N, int Kd,
                                               size_t bzStride, size_t czStride) {
  const f16* Bt = BtBase + bzStride * blockIdx.z;
  OutT* C = CBase + czStride * blockIdx.z;
  __shared__ f16 sA[128 * 40];   // +8 pad: breaks pow2 bank stride
  __shared__ f16 sB[128 * 40];
  int tid = threadIdx.x;
  int lane = tid & 63, wave = tid >> 6;
  int quad = lane >> 4, l16 = lane & 15;
  int mBase = blockIdx.y * 128, nBase = blockIdx.x * 128;
  int wm = (wave >> 1) * 64, wn = (wave & 1) * 64;

  f32x4 acc[4][4];
#pragma unroll
  for (int mi = 0; mi < 4; mi++)
#pragma unroll
    for (int ni = 0; ni < 4; ni++) acc[mi][ni] = (f32x4){0.f, 0.f, 0.f, 0.f};

  int r0 = tid >> 2;        // 0..63
  int c0 = (tid & 3) * 8;   // 0,8,16,24
  const f16* Ap = A + (size_t)(mBase + r0) * Kd + c0;
  const f16* Bp = Bt + (size_t)(nBase + r0) * Kd + c0;

  for (int k0 = 0; k0 < Kd; k0 += 32) {
    *(float4*)&sA[r0 * 40 + c0]        = *(const float4*)(Ap + k0);
    *(float4*)&sA[(r0 + 64) * 40 + c0] = *(const float4*)(Ap + (size_t)64 * Kd + k0);
    *(float4*)&sB[r0 * 40 + c0]        = *(const float4*)(Bp + k0);
    *(float4*)&sB[(r0 + 64) * 40 + c0] = *(const float4*)(Bp + (size_t)64 * Kd + k0);
    __syncthreads();
    f16x8 af[4], bf[4];
#pragma unroll
    for (int mi = 0; mi < 4; mi++)
      af[mi] = *(const f16x8*)&sA[(wm + mi * 16 + l16) * 40 + quad * 8];
#pragma unroll
    for (int ni = 0; ni < 4; ni++)
      bf[ni] = *(const f16x8*)&sB[(wn + ni * 16 + l16) * 40 + quad * 8];
#pragma unroll
    for (int mi = 0; mi < 4; mi++)
#pragma unroll
      for (int ni = 0; ni < 4; ni++)
        acc[mi][ni] = __builtin_amdgcn_mfma_f32_16x16x32_f16(af[mi], bf[ni], acc[mi][ni], 0, 0, 0);
    __syncthreads();
  }

#pragma unroll
  for (int mi = 0; mi < 4; mi++) {
    int row = mBase + wm + mi * 16 + quad * 4;
#pragma unroll
    for (int ni = 0; ni < 4; ni++) {
      int col = nBase + wn + ni * 16 + l16;
      OutT* Cp = C + (size_t)row * N + col;
#pragma unroll
      for (int r = 0; r < 4; r++) Cp[(size_t)r * N] = (OutT)acc[mi][ni][r];
    }
  }
}

// ---------------- sliding-tile flash attention ----------------
// grid (T=32 tiles, NH=32, B=2), 256 threads. Q tile [128 x 64] resident.
// 8 chunks of 64 keys (4 window tiles x 2 halves), online softmax.
__global__ __launch_bounds__(256) void attn_kernel(const f16* __restrict__ Q,
                                                   const f16* __restrict__ Kg,
                                                   const f16* __restrict__ V,
                                                   f16* __restrict__ O) {
  __shared__ f16 sQ[128 * 72];
  __shared__ f16 sK[64 * 72];
  __shared__ f16 sVt[64 * 72];   // V transposed: [d][key]
  __shared__ f16 sP[128 * 72];   // P in A-operand layout source

  int t = blockIdx.x, h = blockIdx.y, b = blockIdx.z;
  int nth_i = t >> 2, ntw_i = t & 3;    // Ht=8, Wt=4
  int tid = threadIdx.x;
  int lane = tid & 63, wave = tid >> 6;
  int quad = lane >> 4, l16 = lane & 15;
  const size_t bstride = (size_t)N_SEQ * K_HID;
  const f16* Qb = Q + (size_t)b * bstride + h * 64;
  const f16* Kb = Kg + (size_t)b * bstride + h * 64;
  const f16* Vb = V + (size_t)b * bstride + h * 64;

  // load Q tile: row qr -> token s = (nth*8 + qr/16)*64 + ntw*16 + qr%16
  for (int i = tid; i < 1024; i += 256) {
    int qr = i >> 3, dc = (i & 7) * 8;
    int s = (nth_i * 8 + (qr >> 4)) * 64 + ntw_i * 16 + (qr & 15);
    *(float4*)&sQ[qr * 72 + dc] = *(const float4*)&Qb[(size_t)s * K_HID + dc];
  }
  __syncthreads();

  f16x8 qf[2][2];   // [q-subtile][k-step], kept in regs for all chunks
#pragma unroll
  for (int qs = 0; qs < 2; qs++)
#pragma unroll
    for (int kk = 0; kk < 2; kk++)
      qf[qs][kk] = *(const f16x8*)&sQ[(wave * 32 + qs * 16 + l16) * 72 + kk * 32 + quad * 8];

  f32x4 oacc[2][4];   // [q-subtile][d-subtile], rows quad*4+r
#pragma unroll
  for (int qs = 0; qs < 2; qs++)
#pragma unroll
    for (int dt = 0; dt < 4; dt++) oacc[qs][dt] = (f32x4){0.f, 0.f, 0.f, 0.f};
  float mrow[2][4], lrow[2][4];
#pragma unroll
  for (int qs = 0; qs < 2; qs++)
#pragma unroll
    for (int r = 0; r < 4; r++) { mrow[qs][r] = -1e30f; lrow[qs][r] = 0.f; }

  int cr = min(max(nth_i, 1), 7);   // clamped window center (tile units)
  int cc = min(max(ntw_i, 1), 3);

  for (int c = 0; c < 8; c++) {
    int kt = c >> 1, half = c & 1;
    int ti = cr - 1 + (kt >> 1), tj = cc - 1 + (kt & 1);
    // stage K chunk [64 x 64] and V^T chunk [64 x 64]
    for (int i = tid; i < 512; i += 256) {
      int kl = i >> 3, dc = (i & 7) * 8;
      int kr = half * 64 + kl;
      int s = (ti * 8 + (kr >> 4)) * 64 + tj * 16 + (kr & 15);
      *(float4*)&sK[kl * 72 + dc] = *(const float4*)&Kb[(size_t)s * K_HID + dc];
      f16x8 vv = *(const f16x8*)&Vb[(size_t)s * K_HID + dc];
#pragma unroll
      for (int j = 0; j < 8; j++) sVt[(dc + j) * 72 + kl] = vv[j];
    }
    __syncthreads();

    // S = Q K^T  (raw, scale applied later)
    f32x4 sacc[2][4];
#pragma unroll
    for (int qs = 0; qs < 2; qs++)
#pragma unroll
      for (int ks = 0; ks < 4; ks++) sacc[qs][ks] = (f32x4){0.f, 0.f, 0.f, 0.f};
#pragma unroll
    for (int ks = 0; ks < 4; ks++) {
      f16x8 kf0 = *(const f16x8*)&sK[(ks * 16 + l16) * 72 + quad * 8];
      f16x8 kf1 = *(const f16x8*)&sK[(ks * 16 + l16) * 72 + 32 + quad * 8];
#pragma unroll
      for (int qs = 0; qs < 2; qs++) {
        sacc[qs][ks] = __builtin_amdgcn_mfma_f32_16x16x32_f16(qf[qs][0], kf0, sacc[qs][ks], 0, 0, 0);
        sacc[qs][ks] = __builtin_amdgcn_mfma_f32_16x16x32_f16(qf[qs][1], kf1, sacc[qs][ks], 0, 0, 0);
      }
    }

    // online softmax; row owned by 16 lanes sharing quad -> shfl_xor 1,2,4,8
#pragma unroll
    for (int qs = 0; qs < 2; qs++) {
#pragma unroll
      for (int r = 0; r < 4; r++) {
        float mx = fmaxf(fmaxf(sacc[qs][0][r], sacc[qs][1][r]),
                         fmaxf(sacc[qs][2][r], sacc[qs][3][r]));
        for (int d = 1; d < 16; d <<= 1) mx = fmaxf(mx, __shfl_xor(mx, d, 64));
        mx *= 0.125f;   // SCALE = 1/sqrt(64)
        float mold = mrow[qs][r];
        float mnew = fmaxf(mold, mx);
        mrow[qs][r] = mnew;
        float alpha = __expf(mold - mnew);   // mold=-1e30 -> alpha=0
        lrow[qs][r] *= alpha;
#pragma unroll
        for (int dt = 0; dt < 4; dt++) oacc[qs][dt][r] *= alpha;
      }
#pragma unroll
      for (int ks = 0; ks < 4; ks++) {
#pragma unroll
        for (int r = 0; r < 4; r++) {
          float p = __expf(sacc[qs][ks][r] * 0.125f - mrow[qs][r]);
          lrow[qs][r] += p;   // lane-partial rowsum; reduced at the end
          sP[(wave * 32 + qs * 16 + quad * 4 + r) * 72 + ks * 16 + l16] = (f16)p;
        }
      }
    }
    __syncthreads();

    // O += P V
#pragma unroll
    for (int kk = 0; kk < 2; kk++) {
      f16x8 pf[2];
#pragma unroll
      for (int qs = 0; qs < 2; qs++)
        pf[qs] = *(const f16x8*)&sP[(wave * 32 + qs * 16 + l16) * 72 + kk * 32 + quad * 8];
#pragma unroll
      for (int dt = 0; dt < 4; dt++) {
        f16x8 vf = *(const f16x8*)&sVt[(dt * 16 + l16) * 72 + kk * 32 + quad * 8];
#pragma unroll
        for (int qs = 0; qs < 2; qs++)
          oacc[qs][dt] = __builtin_amdgcn_mfma_f32_16x16x32_f16(pf[qs], vf, oacc[qs][dt], 0, 0, 0);
      }
    }
    __syncthreads();
  }

  // finalize: reduce lane-partial l across the 16 lanes of the quad, divide, store
  f16* Ob = O + (size_t)b * bstride + h * 64;
#pragma unroll
  for (int qs = 0; qs < 2; qs++) {
#pragma unroll
    for (int r = 0; r < 4; r++) {
      float l = lrow[qs][r];
      for (int d = 1; d < 16; d <<= 1) l += __shfl_xor(l, d, 64);
      float inv = 1.0f / l;
      int qr = wave * 32 + qs * 16 + quad * 4 + r;
      int s = (nth_i * 8 + (qr >> 4)) * 64 + ntw_i * 16 + (qr & 15);
#pragma unroll
      for (int dt = 0; dt < 4; dt++)
        Ob[(size_t)s * K_HID + dt * 16 + l16] = (f16)(oacc[qs][dt][r] * inv);
    }
  }
}

extern "C" void kernel_launch(void* const* d_in, const int* in_sizes, int n_in,
                              void* d_out, int out_size, void* d_ws, size_t ws_size,
                              hipStream_t stream) {
  const float* hs = (const float*)d_in[0];
  const float* Wq = (const float*)d_in[1];
  const float* Wk = (const float*)d_in[2];
  const float* Wv = (const float*)d_in[3];
  const float* Wo = (const float*)d_in[4];
  float* out = (float*)d_out;

  char* ws = (char*)d_ws;
  const size_t WELEM = (size_t)K_HID * K_HID;      // 4,194,304
  const size_t XELEM = (size_t)M_ROWS * K_HID;     // 16,777,216
  f16* WT = (f16*)ws;  ws += 4 * WELEM * sizeof(f16);  // WqT,WkT,WvT,WoT contiguous
  f16* Xh = (f16*)ws;  ws += XELEM * sizeof(f16);
  f16* Qb = (f16*)ws;  ws += XELEM * sizeof(f16);      // Q,K,V contiguous (gemm z-stride)
  f16* Kb = (f16*)ws;  ws += XELEM * sizeof(f16);
  f16* Vb = (f16*)ws;  ws += XELEM * sizeof(f16);
  f16* Ob = (f16*)ws;  ws += XELEM * sizeof(f16);

  // 1. X -> f16
  cvt_f32_to_f16<<<(int)(XELEM / (256 * 8)), 256, 0, stream>>>(hs, Xh, (int)XELEM);
  // 2. transpose+convert all 4 weights
  transpose_cvt<<<dim3(64, 64, 4), 256, 0, stream>>>(Wq, Wk, Wv, Wo, WT);
  // 3. fused Q/K/V projections (grid.z selects weight & output)
  gemm_bt<f16><<<dim3(16, 64, 3), 256, 0, stream>>>(Xh, WT, Qb, M_ROWS, K_HID, K_HID,
                                                    WELEM, XELEM);
  // 4. sliding-tile attention
  attn_kernel<<<dim3(32, 32, 2), 256, 0, stream>>>(Qb, Kb, Vb, Ob);
  // 5. output projection -> fp32 d_out
  gemm_bt<float><<<dim3(16, 64, 1), 256, 0, stream>>>(Ob, WT + 3 * WELEM, out,
                                                      M_ROWS, K_HID, K_HID, 0, 0);
}

// Round 2
// 681.033 us; speedup vs baseline: 1.0221x; 1.0221x over previous
//
#include <hip/hip_runtime.h>
#include <math.h>

typedef _Float16 f16;
typedef _Float16 f16x8 __attribute__((ext_vector_type(8)));
typedef float f32x4 __attribute__((ext_vector_type(4)));

#define K_HID 2048
#define N_SEQ 4096
#define N_BATCH 2
#define M_ROWS 8192   // B*S

// async global->LDS, 16B per lane. LDS dest must be WAVE-UNIFORM base;
// HW writes lane i at base + i*16 (lane-contiguous, no padding allowed).
__device__ __forceinline__ void gl2lds16(const f16* g, f16* l) {
  auto gp = (const __attribute__((address_space(1))) unsigned*)(unsigned long long)(uintptr_t)g;
  auto lp = (__attribute__((address_space(3))) unsigned*)(unsigned)(uintptr_t)l;
  __builtin_amdgcn_global_load_lds(gp, lp, 16, 0, 0);
}

// ---------------- f32 -> f16 conversion (8 elems/thread) ----------------
__global__ __launch_bounds__(256) void cvt_f32_to_f16(const float* __restrict__ x,
                                                      f16* __restrict__ y, int n) {
  int i = (blockIdx.x * 256 + threadIdx.x) * 8;
  if (i >= n) return;
  float4 a = *(const float4*)(x + i);
  float4 b = *(const float4*)(x + i + 4);
  f16x8 o;
  o[0] = (f16)a.x; o[1] = (f16)a.y; o[2] = (f16)a.z; o[3] = (f16)a.w;
  o[4] = (f16)b.x; o[5] = (f16)b.y; o[6] = (f16)b.z; o[7] = (f16)b.w;
  *(f16x8*)(y + i) = o;
}

// -------- weight transpose+convert: W[K][N] f32 -> Wt[N][K] f16 ----------
__global__ __launch_bounds__(256) void transpose_cvt(const float* __restrict__ W0,
                                                     const float* __restrict__ W1,
                                                     const float* __restrict__ W2,
                                                     const float* __restrict__ W3,
                                                     f16* __restrict__ WT) {
  const float* W = (blockIdx.z == 0) ? W0 : (blockIdx.z == 1) ? W1
                 : (blockIdx.z == 2) ? W2 : W3;
  f16* Wt = WT + (size_t)blockIdx.z * K_HID * K_HID;
  __shared__ float tile[32][33];
  int bx = blockIdx.x * 32;   // n base
  int by = blockIdx.y * 32;   // k base
  int x = threadIdx.x & 31;
  int y = threadIdx.x >> 5;   // 0..7
  for (int i = 0; i < 32; i += 8)
    tile[y + i][x] = W[(size_t)(by + y + i) * K_HID + bx + x];
  __syncthreads();
  for (int i = 0; i < 32; i += 8)
    Wt[(size_t)(bx + y + i) * K_HID + by + x] = (f16)tile[x][y + i];
}

// ---------------- GEMM: C[M][N] = A[M][K] * Bt[N][K]^T ----------------
// 128x128 tile, BK=32, 256 threads. Staging via global_load_lds width=16:
// each wave issues 4 async loads/iter (2 A-chunks + 2 B-chunks of 16 rows),
// LDS layout unpadded row-major [128][32] (required: lane-contiguous dest).
template <typename OutT>
__global__ __launch_bounds__(256) void gemm_bt(const f16* __restrict__ A,
                                               const f16* __restrict__ BtBase,
                                               OutT* __restrict__ CBase,
                                               int M, int N, int Kd,
                                               size_t bzStride, size_t czStride) {
  const f16* Bt = BtBase + bzStride * blockIdx.z;
  OutT* C = CBase + czStride * blockIdx.z;
  __shared__ f16 sA[128 * 32];
  __shared__ f16 sB[128 * 32];
  int tid = threadIdx.x;
  int lane = tid & 63, wave = tid >> 6;
  int quad = lane >> 4, l16 = lane & 15;
  int mBase = blockIdx.y * 128, nBase = blockIdx.x * 128;
  int wm = (wave >> 1) * 64, wn = (wave & 1) * 64;

  f32x4 acc[4][4];
#pragma unroll
  for (int mi = 0; mi < 4; mi++)
#pragma unroll
    for (int ni = 0; ni < 4; ni++) acc[mi][ni] = (f32x4){0.f, 0.f, 0.f, 0.f};

  // wave w stages A rows [w*32, w*32+32) and B rows [w*32, w*32+32)
  int rL = lane >> 2;          // 0..15 (row within 16-row chunk)
  int cL = (lane & 3) * 8;     // 0,8,16,24
  const f16* Ap0 = A + (size_t)(mBase + wave * 32 + rL) * Kd + cL;
  const f16* Ap1 = Ap0 + (size_t)16 * Kd;
  const f16* Bp0 = Bt + (size_t)(nBase + wave * 32 + rL) * Kd + cL;
  const f16* Bp1 = Bp0 + (size_t)16 * Kd;
  f16* lA0 = &sA[(wave * 32) * 32];        // wave-uniform LDS bases
  f16* lA1 = &sA[(wave * 32 + 16) * 32];
  f16* lB0 = &sB[(wave * 32) * 32];
  f16* lB1 = &sB[(wave * 32 + 16) * 32];

  for (int k0 = 0; k0 < Kd; k0 += 32) {
    gl2lds16(Ap0 + k0, lA0);
    gl2lds16(Ap1 + k0, lA1);
    gl2lds16(Bp0 + k0, lB0);
    gl2lds16(Bp1 + k0, lB1);
    __syncthreads();   // drains vmcnt (global_load_lds) before LDS reads
    f16x8 af[4], bf[4];
#pragma unroll
    for (int mi = 0; mi < 4; mi++)
      af[mi] = *(const f16x8*)&sA[(wm + mi * 16 + l16) * 32 + quad * 8];
#pragma unroll
    for (int ni = 0; ni < 4; ni++)
      bf[ni] = *(const f16x8*)&sB[(wn + ni * 16 + l16) * 32 + quad * 8];
#pragma unroll
    for (int mi = 0; mi < 4; mi++)
#pragma unroll
      for (int ni = 0; ni < 4; ni++)
        acc[mi][ni] = __builtin_amdgcn_mfma_f32_16x16x32_f16(af[mi], bf[ni], acc[mi][ni], 0, 0, 0);
    __syncthreads();
  }

#pragma unroll
  for (int mi = 0; mi < 4; mi++) {
    int row = mBase + wm + mi * 16 + quad * 4;
#pragma unroll
    for (int ni = 0; ni < 4; ni++) {
      int col = nBase + wn + ni * 16 + l16;
      OutT* Cp = C + (size_t)row * N + col;
#pragma unroll
      for (int r = 0; r < 4; r++) Cp[(size_t)r * N] = (OutT)acc[mi][ni][r];
    }
  }
}

// ---------------- sliding-tile flash attention ----------------
// grid (T=32 tiles, NH=32, B=2), 256 threads. Q tile [128 x 64] resident.
// 8 chunks of 64 keys (4 window tiles x 2 halves), online softmax (base-2).
// sVt uses XOR block-swizzle col' = col ^ (row & 56): breaks the 8-way
// same-bank conflict of transpose writes (rows 8 apart) while keeping
// fragment reads a single b128 (swizzle flips 8-key blocks only).
__global__ __launch_bounds__(256) void attn_kernel(const f16* __restrict__ Q,
                                                   const f16* __restrict__ Kg,
                                                   const f16* __restrict__ V,
                                                   f16* __restrict__ O) {
  __shared__ f16 sQ[128 * 72];
  __shared__ f16 sK[64 * 72];
  __shared__ f16 sVt[64 * 72];   // V transposed: [d][key ^ (d&56)]
  __shared__ f16 sP[128 * 72];   // P staged for A-operand layout

  int t = blockIdx.x, h = blockIdx.y, b = blockIdx.z;
  int nth_i = t >> 2, ntw_i = t & 3;    // Ht=8, Wt=4
  int tid = threadIdx.x;
  int lane = tid & 63, wave = tid >> 6;
  int quad = lane >> 4, l16 = lane & 15;
  const size_t bstride = (size_t)N_SEQ * K_HID;
  const f16* Qb = Q + (size_t)b * bstride + h * 64;
  const f16* Kb = Kg + (size_t)b * bstride + h * 64;
  const f16* Vb = V + (size_t)b * bstride + h * 64;

  const float SC2 = 0.18033688f;   // (1/sqrt(64)) * log2(e)

  // load Q tile: row qr -> token s = (nth*8 + qr/16)*64 + ntw*16 + qr%16
  for (int i = tid; i < 1024; i += 256) {
    int qr = i >> 3, dc = (i & 7) * 8;
    int s = (nth_i * 8 + (qr >> 4)) * 64 + ntw_i * 16 + (qr & 15);
    *(float4*)&sQ[qr * 72 + dc] = *(const float4*)&Qb[(size_t)s * K_HID + dc];
  }
  __syncthreads();

  f16x8 qf[2][2];   // [q-subtile][k-step], resident for all chunks
#pragma unroll
  for (int qs = 0; qs < 2; qs++)
#pragma unroll
    for (int kk = 0; kk < 2; kk++)
      qf[qs][kk] = *(const f16x8*)&sQ[(wave * 32 + qs * 16 + l16) * 72 + kk * 32 + quad * 8];

  f32x4 oacc[2][4];
#pragma unroll
  for (int qs = 0; qs < 2; qs++)
#pragma unroll
    for (int dt = 0; dt < 4; dt++) oacc[qs][dt] = (f32x4){0.f, 0.f, 0.f, 0.f};
  float mrow[2][4], lrow[2][4];
#pragma unroll
  for (int qs = 0; qs < 2; qs++)
#pragma unroll
    for (int r = 0; r < 4; r++) { mrow[qs][r] = -1e30f; lrow[qs][r] = 0.f; }

  int cr = min(max(nth_i, 1), 7);   // clamped window center (tile units)
  int cc = min(max(ntw_i, 1), 3);

  for (int c = 0; c < 8; c++) {
    int kt = c >> 1, half = c & 1;
    int ti = cr - 1 + (kt >> 1), tj = cc - 1 + (kt & 1);
    // stage K chunk [64 x 64] and swizzled V^T chunk
    for (int i = tid; i < 512; i += 256) {
      int kl = i >> 3, dc = (i & 7) * 8;
      int kr = half * 64 + kl;
      int s = (ti * 8 + (kr >> 4)) * 64 + tj * 16 + (kr & 15);
      *(float4*)&sK[kl * 72 + dc] = *(const float4*)&Kb[(size_t)s * K_HID + dc];
      f16x8 vv = *(const f16x8*)&Vb[(size_t)s * K_HID + dc];
      int sw = kl ^ dc;   // dc == (row & 56) for rows dc..dc+7
#pragma unroll
      for (int j = 0; j < 8; j++) sVt[(dc + j) * 72 + sw] = vv[j];
    }
    __syncthreads();

    // S = Q K^T (raw logits; scale folded into base-2 softmax)
    f32x4 sacc[2][4];
#pragma unroll
    for (int qs = 0; qs < 2; qs++)
#pragma unroll
      for (int ks = 0; ks < 4; ks++) sacc[qs][ks] = (f32x4){0.f, 0.f, 0.f, 0.f};
#pragma unroll
    for (int ks = 0; ks < 4; ks++) {
      f16x8 kf0 = *(const f16x8*)&sK[(ks * 16 + l16) * 72 + quad * 8];
      f16x8 kf1 = *(const f16x8*)&sK[(ks * 16 + l16) * 72 + 32 + quad * 8];
#pragma unroll
      for (int qs = 0; qs < 2; qs++) {
        sacc[qs][ks] = __builtin_amdgcn_mfma_f32_16x16x32_f16(qf[qs][0], kf0, sacc[qs][ks], 0, 0, 0);
        sacc[qs][ks] = __builtin_amdgcn_mfma_f32_16x16x32_f16(qf[qs][1], kf1, sacc[qs][ks], 0, 0, 0);
      }
    }

    // online softmax in log2 domain; rows owned by 16 lanes -> shfl_xor 1..8
#pragma unroll
    for (int qs = 0; qs < 2; qs++) {
#pragma unroll
      for (int r = 0; r < 4; r++) {
        float mx = fmaxf(fmaxf(sacc[qs][0][r], sacc[qs][1][r]),
                         fmaxf(sacc[qs][2][r], sacc[qs][3][r]));
        for (int d = 1; d < 16; d <<= 1) mx = fmaxf(mx, __shfl_xor(mx, d, 64));
        mx *= SC2;
        float mold = mrow[qs][r];
        float mnew = fmaxf(mold, mx);
        mrow[qs][r] = mnew;
        float alpha = exp2f(mold - mnew);   // mold=-1e30 -> 0
        lrow[qs][r] *= alpha;
#pragma unroll
        for (int dt = 0; dt < 4; dt++) oacc[qs][dt][r] *= alpha;
      }
#pragma unroll
      for (int ks = 0; ks < 4; ks++) {
#pragma unroll
        for (int r = 0; r < 4; r++) {
          float p = exp2f(sacc[qs][ks][r] * SC2 - mrow[qs][r]);
          lrow[qs][r] += p;   // lane-partial rowsum; reduced at finalize
          sP[(wave * 32 + qs * 16 + quad * 4 + r) * 72 + ks * 16 + l16] = (f16)p;
        }
      }
    }
    __syncthreads();

    // O += P V   (B-frag from swizzled sVt)
#pragma unroll
    for (int kk = 0; kk < 2; kk++) {
      f16x8 pf[2];
#pragma unroll
      for (int qs = 0; qs < 2; qs++)
        pf[qs] = *(const f16x8*)&sP[(wave * 32 + qs * 16 + l16) * 72 + kk * 32 + quad * 8];
#pragma unroll
      for (int dt = 0; dt < 4; dt++) {
        int d = dt * 16 + l16;
        f16x8 vf = *(const f16x8*)&sVt[d * 72 + ((kk * 32 + quad * 8) ^ (d & 56))];
#pragma unroll
        for (int qs = 0; qs < 2; qs++)
          oacc[qs][dt] = __builtin_amdgcn_mfma_f32_16x16x32_f16(pf[qs], vf, oacc[qs][dt], 0, 0, 0);
      }
    }
    __syncthreads();
  }

  // finalize: reduce lane-partial l across the 16 lanes, divide, store
  f16* Ob = O + (size_t)b * bstride + h * 64;
#pragma unroll
  for (int qs = 0; qs < 2; qs++) {
#pragma unroll
    for (int r = 0; r < 4; r++) {
      float l = lrow[qs][r];
      for (int d = 1; d < 16; d <<= 1) l += __shfl_xor(l, d, 64);
      float inv = 1.0f / l;
      int qr = wave * 32 + qs * 16 + quad * 4 + r;
      int s = (nth_i * 8 + (qr >> 4)) * 64 + ntw_i * 16 + (qr & 15);
#pragma unroll
      for (int dt = 0; dt < 4; dt++)
        Ob[(size_t)s * K_HID + dt * 16 + l16] = (f16)(oacc[qs][dt][r] * inv);
    }
  }
}

extern "C" void kernel_launch(void* const* d_in, const int* in_sizes, int n_in,
                              void* d_out, int out_size, void* d_ws, size_t ws_size,
                              hipStream_t stream) {
  const float* hs = (const float*)d_in[0];
  const float* Wq = (const float*)d_in[1];
  const float* Wk = (const float*)d_in[2];
  const float* Wv = (const float*)d_in[3];
  const float* Wo = (const float*)d_in[4];
  float* out = (float*)d_out;

  char* ws = (char*)d_ws;
  const size_t WELEM = (size_t)K_HID * K_HID;      // 4,194,304
  const size_t XELEM = (size_t)M_ROWS * K_HID;     // 16,777,216
  f16* WT = (f16*)ws;  ws += 4 * WELEM * sizeof(f16);  // WqT,WkT,WvT,WoT
  f16* Xh = (f16*)ws;  ws += XELEM * sizeof(f16);
  f16* Qb = (f16*)ws;  ws += XELEM * sizeof(f16);      // Q,K,V contiguous
  f16* Kb = (f16*)ws;  ws += XELEM * sizeof(f16);
  f16* Vb = (f16*)ws;  ws += XELEM * sizeof(f16);
  f16* Ob = (f16*)ws;  ws += XELEM * sizeof(f16);

  cvt_f32_to_f16<<<(int)(XELEM / (256 * 8)), 256, 0, stream>>>(hs, Xh, (int)XELEM);
  transpose_cvt<<<dim3(64, 64, 4), 256, 0, stream>>>(Wq, Wk, Wv, Wo, WT);
  gemm_bt<f16><<<dim3(16, 64, 3), 256, 0, stream>>>(Xh, WT, Qb, M_ROWS, K_HID, K_HID,
                                                    WELEM, XELEM);
  attn_kernel<<<dim3(32, 32, 2), 256, 0, stream>>>(Qb, Kb, Vb, Ob);
  gemm_bt<float><<<dim3(16, 64, 1), 256, 0, stream>>>(Ob, WT + 3 * WELEM, out,
                                                      M_ROWS, K_HID, K_HID, 0, 0);
}

// Round 3
// 671.375 us; speedup vs baseline: 1.0368x; 1.0144x over previous
//
#include <hip/hip_runtime.h>
#include <math.h>

typedef _Float16 f16;
typedef _Float16 f16x8 __attribute__((ext_vector_type(8)));
typedef float f32x4 __attribute__((ext_vector_type(4)));

#define K_HID 2048
#define N_SEQ 4096
#define N_BATCH 2
#define M_ROWS 8192   // B*S

// async global->LDS, 16B per lane. LDS dest must be WAVE-UNIFORM base;
// HW writes lane i at base + i*16 (lane-contiguous, no padding allowed).
__device__ __forceinline__ void gl2lds16(const f16* g, f16* l) {
  auto gp = (const __attribute__((address_space(1))) unsigned*)(unsigned long long)(uintptr_t)g;
  auto lp = (__attribute__((address_space(3))) unsigned*)(unsigned)(uintptr_t)l;
  __builtin_amdgcn_global_load_lds(gp, lp, 16, 0, 0);
}

// ---------------- f32 -> f16 conversion (8 elems/thread) ----------------
__global__ __launch_bounds__(256) void cvt_f32_to_f16(const float* __restrict__ x,
                                                      f16* __restrict__ y, int n) {
  int i = (blockIdx.x * 256 + threadIdx.x) * 8;
  if (i >= n) return;
  float4 a = *(const float4*)(x + i);
  float4 b = *(const float4*)(x + i + 4);
  f16x8 o;
  o[0] = (f16)a.x; o[1] = (f16)a.y; o[2] = (f16)a.z; o[3] = (f16)a.w;
  o[4] = (f16)b.x; o[5] = (f16)b.y; o[6] = (f16)b.z; o[7] = (f16)b.w;
  *(f16x8*)(y + i) = o;
}

// -------- weight transpose+convert: W[K][N] f32 -> Wt[N][K] f16 ----------
__global__ __launch_bounds__(256) void transpose_cvt(const float* __restrict__ W0,
                                                     const float* __restrict__ W1,
                                                     const float* __restrict__ W2,
                                                     const float* __restrict__ W3,
                                                     f16* __restrict__ WT) {
  const float* W = (blockIdx.z == 0) ? W0 : (blockIdx.z == 1) ? W1
                 : (blockIdx.z == 2) ? W2 : W3;
  f16* Wt = WT + (size_t)blockIdx.z * K_HID * K_HID;
  __shared__ float tile[32][33];
  int bx = blockIdx.x * 32;   // n base
  int by = blockIdx.y * 32;   // k base
  int x = threadIdx.x & 31;
  int y = threadIdx.x >> 5;   // 0..7
  for (int i = 0; i < 32; i += 8)
    tile[y + i][x] = W[(size_t)(by + y + i) * K_HID + bx + x];
  __syncthreads();
  for (int i = 0; i < 32; i += 8)
    Wt[(size_t)(bx + y + i) * K_HID + by + x] = (f16)tile[x][y + i];
}

// ---------------- GEMM: C[M][N] = A[M][K] * Bt[N][K]^T ----------------
// 128x128 tile, BK=32, 256 threads, global_load_lds width=16 staging.
// LDS is unpadded [128][32] (gl2lds requires lane-contiguous dest) with an
// XOR chunk swizzle: row r stores global 8-f16 chunk c at chunk c^((r>>1)&3).
// This makes both gl2lds writes and ds_read_b128 fragment reads bank-uniform
// per 32-lane half (the unswizzled layout left 16 of 32 banks idle -> the
// 2.5e7 SQ_LDS_BANK_CONFLICT seen in round 2).
template <typename OutT>
__global__ __launch_bounds__(256) void gemm_bt(const f16* __restrict__ A,
                                               const f16* __restrict__ BtBase,
                                               OutT* __restrict__ CBase,
                                               int M, int N, int Kd,
                                               size_t bzStride, size_t czStride) {
  const f16* Bt = BtBase + bzStride * blockIdx.z;
  OutT* C = CBase + czStride * blockIdx.z;
  __shared__ f16 sA[128 * 32];
  __shared__ f16 sB[128 * 32];
  int tid = threadIdx.x;
  int lane = tid & 63, wave = tid >> 6;
  int quad = lane >> 4, l16 = lane & 15;
  int mBase = blockIdx.y * 128, nBase = blockIdx.x * 128;
  int wm = (wave >> 1) * 64, wn = (wave & 1) * 64;

  f32x4 acc[4][4];
#pragma unroll
  for (int mi = 0; mi < 4; mi++)
#pragma unroll
    for (int ni = 0; ni < 4; ni++) acc[mi][ni] = (f32x4){0.f, 0.f, 0.f, 0.f};

  // staging: wave w covers A rows [w*32,+32) and B rows [w*32,+32), two
  // 16-row chunks each. lane -> row rr=lane>>2, fetches SWIZZLED col chunk.
  int rL = lane >> 2;                              // 0..15
  int cSw = ((lane & 3) ^ ((lane >> 3) & 3)) * 8;  // swizzled 8-f16 chunk
  const f16* Ap0 = A + (size_t)(mBase + wave * 32 + rL) * Kd + cSw;
  const f16* Ap1 = Ap0 + (size_t)16 * Kd;
  const f16* Bp0 = Bt + (size_t)(nBase + wave * 32 + rL) * Kd + cSw;
  const f16* Bp1 = Bp0 + (size_t)16 * Kd;
  f16* lA0 = &sA[(wave * 32) * 32];        // wave-uniform LDS bases
  f16* lA1 = &sA[(wave * 32 + 16) * 32];
  f16* lB0 = &sB[(wave * 32) * 32];
  f16* lB1 = &sB[(wave * 32 + 16) * 32];

  // fragment read: global chunk quad lives at LDS chunk quad^((l16>>1)&3)
  int rdOff = (quad ^ ((l16 >> 1) & 3)) * 8;

  for (int k0 = 0; k0 < Kd; k0 += 32) {
    gl2lds16(Ap0 + k0, lA0);
    gl2lds16(Ap1 + k0, lA1);
    gl2lds16(Bp0 + k0, lB0);
    gl2lds16(Bp1 + k0, lB1);
    __syncthreads();   // drains vmcnt (global_load_lds) before LDS reads
    f16x8 af[4], bf[4];
#pragma unroll
    for (int mi = 0; mi < 4; mi++)
      af[mi] = *(const f16x8*)&sA[(wm + mi * 16 + l16) * 32 + rdOff];
#pragma unroll
    for (int ni = 0; ni < 4; ni++)
      bf[ni] = *(const f16x8*)&sB[(wn + ni * 16 + l16) * 32 + rdOff];
#pragma unroll
    for (int mi = 0; mi < 4; mi++)
#pragma unroll
      for (int ni = 0; ni < 4; ni++)
        acc[mi][ni] = __builtin_amdgcn_mfma_f32_16x16x32_f16(af[mi], bf[ni], acc[mi][ni], 0, 0, 0);
    __syncthreads();
  }

#pragma unroll
  for (int mi = 0; mi < 4; mi++) {
    int row = mBase + wm + mi * 16 + quad * 4;
#pragma unroll
    for (int ni = 0; ni < 4; ni++) {
      int col = nBase + wn + ni * 16 + l16;
      OutT* Cp = C + (size_t)row * N + col;
#pragma unroll
      for (int r = 0; r < 4; r++) Cp[(size_t)r * N] = (OutT)acc[mi][ni][r];
    }
  }
}

// ---------------- sliding-tile flash attention ----------------
// grid (T=32 tiles, NH=32, B=2), 256 threads. Q tile [128 x 64] resident.
// 8 chunks of 64 keys (4 window tiles x 2 halves), online softmax (base-2).
// sVt uses XOR block-swizzle col' = col ^ (row & 56): breaks the 8-way
// same-bank conflict of transpose writes while keeping b128 fragment reads.
__global__ __launch_bounds__(256) void attn_kernel(const f16* __restrict__ Q,
                                                   const f16* __restrict__ Kg,
                                                   const f16* __restrict__ V,
                                                   f16* __restrict__ O) {
  __shared__ f16 sQ[128 * 72];
  __shared__ f16 sK[64 * 72];
  __shared__ f16 sVt[64 * 72];   // V transposed: [d][key ^ (d&56)]
  __shared__ f16 sP[128 * 72];   // P staged for A-operand layout

  int t = blockIdx.x, h = blockIdx.y, b = blockIdx.z;
  int nth_i = t >> 2, ntw_i = t & 3;    // Ht=8, Wt=4
  int tid = threadIdx.x;
  int lane = tid & 63, wave = tid >> 6;
  int quad = lane >> 4, l16 = lane & 15;
  const size_t bstride = (size_t)N_SEQ * K_HID;
  const f16* Qb = Q + (size_t)b * bstride + h * 64;
  const f16* Kb = Kg + (size_t)b * bstride + h * 64;
  const f16* Vb = V + (size_t)b * bstride + h * 64;

  const float SC2 = 0.18033688f;   // (1/sqrt(64)) * log2(e)

  // load Q tile: row qr -> token s = (nth*8 + qr/16)*64 + ntw*16 + qr%16
  for (int i = tid; i < 1024; i += 256) {
    int qr = i >> 3, dc = (i & 7) * 8;
    int s = (nth_i * 8 + (qr >> 4)) * 64 + ntw_i * 16 + (qr & 15);
    *(float4*)&sQ[qr * 72 + dc] = *(const float4*)&Qb[(size_t)s * K_HID + dc];
  }
  __syncthreads();

  f16x8 qf[2][2];   // [q-subtile][k-step], resident for all chunks
#pragma unroll
  for (int qs = 0; qs < 2; qs++)
#pragma unroll
    for (int kk = 0; kk < 2; kk++)
      qf[qs][kk] = *(const f16x8*)&sQ[(wave * 32 + qs * 16 + l16) * 72 + kk * 32 + quad * 8];

  f32x4 oacc[2][4];
#pragma unroll
  for (int qs = 0; qs < 2; qs++)
#pragma unroll
    for (int dt = 0; dt < 4; dt++) oacc[qs][dt] = (f32x4){0.f, 0.f, 0.f, 0.f};
  float mrow[2][4], lrow[2][4];
#pragma unroll
  for (int qs = 0; qs < 2; qs++)
#pragma unroll
    for (int r = 0; r < 4; r++) { mrow[qs][r] = -1e30f; lrow[qs][r] = 0.f; }

  int cr = min(max(nth_i, 1), 7);   // clamped window center (tile units)
  int cc = min(max(ntw_i, 1), 3);

  for (int c = 0; c < 8; c++) {
    int kt = c >> 1, half = c & 1;
    int ti = cr - 1 + (kt >> 1), tj = cc - 1 + (kt & 1);
    // stage K chunk [64 x 64] and swizzled V^T chunk
    for (int i = tid; i < 512; i += 256) {
      int kl = i >> 3, dc = (i & 7) * 8;
      int kr = half * 64 + kl;
      int s = (ti * 8 + (kr >> 4)) * 64 + tj * 16 + (kr & 15);
      *(float4*)&sK[kl * 72 + dc] = *(const float4*)&Kb[(size_t)s * K_HID + dc];
      f16x8 vv = *(const f16x8*)&Vb[(size_t)s * K_HID + dc];
      int sw = kl ^ dc;   // dc == (row & 56) for rows dc..dc+7
#pragma unroll
      for (int j = 0; j < 8; j++) sVt[(dc + j) * 72 + sw] = vv[j];
    }
    __syncthreads();

    // S = Q K^T (raw logits; scale folded into base-2 softmax)
    f32x4 sacc[2][4];
#pragma unroll
    for (int qs = 0; qs < 2; qs++)
#pragma unroll
      for (int ks = 0; ks < 4; ks++) sacc[qs][ks] = (f32x4){0.f, 0.f, 0.f, 0.f};
#pragma unroll
    for (int ks = 0; ks < 4; ks++) {
      f16x8 kf0 = *(const f16x8*)&sK[(ks * 16 + l16) * 72 + quad * 8];
      f16x8 kf1 = *(const f16x8*)&sK[(ks * 16 + l16) * 72 + 32 + quad * 8];
#pragma unroll
      for (int qs = 0; qs < 2; qs++) {
        sacc[qs][ks] = __builtin_amdgcn_mfma_f32_16x16x32_f16(qf[qs][0], kf0, sacc[qs][ks], 0, 0, 0);
        sacc[qs][ks] = __builtin_amdgcn_mfma_f32_16x16x32_f16(qf[qs][1], kf1, sacc[qs][ks], 0, 0, 0);
      }
    }

    // online softmax in log2 domain; rows owned by 16 lanes -> shfl_xor 1..8
#pragma unroll
    for (int qs = 0; qs < 2; qs++) {
#pragma unroll
      for (int r = 0; r < 4; r++) {
        float mx = fmaxf(fmaxf(sacc[qs][0][r], sacc[qs][1][r]),
                         fmaxf(sacc[qs][2][r], sacc[qs][3][r]));
        for (int d = 1; d < 16; d <<= 1) mx = fmaxf(mx, __shfl_xor(mx, d, 64));
        mx *= SC2;
        float mold = mrow[qs][r];
        float mnew = fmaxf(mold, mx);
        mrow[qs][r] = mnew;
        float alpha = exp2f(mold - mnew);   // mold=-1e30 -> 0
        lrow[qs][r] *= alpha;
#pragma unroll
        for (int dt = 0; dt < 4; dt++) oacc[qs][dt][r] *= alpha;
      }
#pragma unroll
      for (int ks = 0; ks < 4; ks++) {
#pragma unroll
        for (int r = 0; r < 4; r++) {
          float p = exp2f(sacc[qs][ks][r] * SC2 - mrow[qs][r]);
          lrow[qs][r] += p;   // lane-partial rowsum; reduced at finalize
          sP[(wave * 32 + qs * 16 + quad * 4 + r) * 72 + ks * 16 + l16] = (f16)p;
        }
      }
    }
    __syncthreads();

    // O += P V   (B-frag from swizzled sVt)
#pragma unroll
    for (int kk = 0; kk < 2; kk++) {
      f16x8 pf[2];
#pragma unroll
      for (int qs = 0; qs < 2; qs++)
        pf[qs] = *(const f16x8*)&sP[(wave * 32 + qs * 16 + l16) * 72 + kk * 32 + quad * 8];
#pragma unroll
      for (int dt = 0; dt < 4; dt++) {
        int d = dt * 16 + l16;
        f16x8 vf = *(const f16x8*)&sVt[d * 72 + ((kk * 32 + quad * 8) ^ (d & 56))];
#pragma unroll
        for (int qs = 0; qs < 2; qs++)
          oacc[qs][dt] = __builtin_amdgcn_mfma_f32_16x16x32_f16(pf[qs], vf, oacc[qs][dt], 0, 0, 0);
      }
    }
    __syncthreads();
  }

  // finalize: reduce lane-partial l across the 16 lanes, divide, store
  f16* Ob = O + (size_t)b * bstride + h * 64;
#pragma unroll
  for (int qs = 0; qs < 2; qs++) {
#pragma unroll
    for (int r = 0; r < 4; r++) {
      float l = lrow[qs][r];
      for (int d = 1; d < 16; d <<= 1) l += __shfl_xor(l, d, 64);
      float inv = 1.0f / l;
      int qr = wave * 32 + qs * 16 + quad * 4 + r;
      int s = (nth_i * 8 + (qr >> 4)) * 64 + ntw_i * 16 + (qr & 15);
#pragma unroll
      for (int dt = 0; dt < 4; dt++)
        Ob[(size_t)s * K_HID + dt * 16 + l16] = (f16)(oacc[qs][dt][r] * inv);
    }
  }
}

extern "C" void kernel_launch(void* const* d_in, const int* in_sizes, int n_in,
                              void* d_out, int out_size, void* d_ws, size_t ws_size,
                              hipStream_t stream) {
  const float* hs = (const float*)d_in[0];
  const float* Wq = (const float*)d_in[1];
  const float* Wk = (const float*)d_in[2];
  const float* Wv = (const float*)d_in[3];
  const float* Wo = (const float*)d_in[4];
  float* out = (float*)d_out;

  char* ws = (char*)d_ws;
  const size_t WELEM = (size_t)K_HID * K_HID;      // 4,194,304
  const size_t XELEM = (size_t)M_ROWS * K_HID;     // 16,777,216
  f16* WT = (f16*)ws;  ws += 4 * WELEM * sizeof(f16);  // WqT,WkT,WvT,WoT
  f16* Xh = (f16*)ws;  ws += XELEM * sizeof(f16);
  f16* Qb = (f16*)ws;  ws += XELEM * sizeof(f16);      // Q,K,V contiguous
  f16* Kb = (f16*)ws;  ws += XELEM * sizeof(f16);
  f16* Vb = (f16*)ws;  ws += XELEM * sizeof(f16);
  f16* Ob = (f16*)ws;  ws += XELEM * sizeof(f16);

  cvt_f32_to_f16<<<(int)(XELEM / (256 * 8)), 256, 0, stream>>>(hs, Xh, (int)XELEM);
  transpose_cvt<<<dim3(64, 64, 4), 256, 0, stream>>>(Wq, Wk, Wv, Wo, WT);
  gemm_bt<f16><<<dim3(16, 64, 3), 256, 0, stream>>>(Xh, WT, Qb, M_ROWS, K_HID, K_HID,
                                                    WELEM, XELEM);
  attn_kernel<<<dim3(32, 32, 2), 256, 0, stream>>>(Qb, Kb, Vb, Ob);
  gemm_bt<float><<<dim3(16, 64, 1), 256, 0, stream>>>(Ob, WT + 3 * WELEM, out,
                                                      M_ROWS, K_HID, K_HID, 0, 0);
}